// Round 5
// baseline (129.091 us; speedup 1.0000x reference)
//
#include <hip/hip_runtime.h>
#include <hip/hip_bf16.h>
#include <math.h>

namespace {
typedef __attribute__((ext_vector_type(8)))  short  short8;   // 8 bf16 (MFMA A/B frag)
typedef __attribute__((ext_vector_type(4)))  float  floatx4;  // MFMA C/D frag

constexpr int Bc = 16;    // batch
constexpr int DC = 16;    // deep channels
constexpr int ND = 1024;  // deep length
constexpr int C  = 64;    // c_in
constexpr int N  = 4096;  // sequence
constexpr int CO = 128;   // c_out
constexpr int KW = 7;
constexpr int F  = C * KW;     // 448
constexpr int LT = 32;         // l-tile in k2
constexpr int PLD = F + 8;     // 456 bf16/row (912 B, 16B-aligned rows)
constexpr int GPS = 560;       // per-(b,chunk) Gram slot: G0[256] G1[256] s[16] d0[16] dN[16]

// workspace layout (bytes)
constexpr size_t WB_OFF = 0;            // bf16 fc_w: 57344*2 = 114688
constexpr size_t GP_OFF = 131072;       // 16*8*560*4 = 286720
constexpr size_t XT_OFF = 524288;       // bf16 x transposed [b][n][c]: 8 MiB

__device__ inline unsigned short f2bf(float f) {
    __hip_bfloat16 h = __float2bfloat16(f);      // RNE
    return __builtin_bit_cast(unsigned short, h);
}
__device__ inline float bf2f(unsigned short u) {
    unsigned int x = ((unsigned int)u) << 16;
    return __builtin_bit_cast(float, x);
}
__device__ inline float rcpf(float x) { return __builtin_amdgcn_rcpf(x); }
__device__ inline int reflect(int p) {          // jnp reflect pad, N=4096
    p = (p < 0) ? -p : p;
    return (p >= N) ? (2 * N - 2 - p) : p;
}

// K0: blocks [0,56): fc_w fp32->bf16.
//     blocks [56,184): per-(b,chunk) Gram partials of deep: G0=sum D_d[t]D_e[t],
//       G1=sum D_d[t]D_e[t+1] (global t<=1022), s=sum_t D_d[t], plus D[:,0], D[:,1023].
//     blocks [184,1208): transpose x[b][c][n] fp32 -> xt[b][n][c] bf16.
__global__ __launch_bounds__(256)
void k0(const float* __restrict__ deep, const float* __restrict__ x,
        const float* __restrict__ fcw, unsigned short* __restrict__ wb,
        float* __restrict__ gp, unsigned short* __restrict__ xt)
{
    __shared__ __align__(16) char sm[9216];
    const int blk = blockIdx.x;
    const int tid = threadIdx.x;

    if (blk < 56) {                                  // fc_w -> bf16
        const int i = (blk * 256 + tid) * 4;         // < 57344
        const float4 v = *(const float4*)(fcw + i);
        ushort4 o;
        o.x = f2bf(v.x); o.y = f2bf(v.y); o.z = f2bf(v.z); o.w = f2bf(v.w);
        *(ushort4*)(wb + i) = o;
        return;
    }
    if (blk < 184) {                                 // Gram partials
        float (*Dch)[132] = (float (*)[132])sm;      // 16 x 132 floats (cols 0..128 used)
        const int i2 = blk - 56;
        const int b  = i2 >> 3;
        const int ch = i2 & 7;
        const int t0 = ch * 128;
        const int d  = tid >> 4;
        const int e  = tid & 15;
#pragma unroll
        for (int p = 0; p < 9; ++p) {
            const int tt = e + 16 * p;
            if (tt < 129)
                Dch[d][tt] = deep[(b * DC + d) * ND + min(t0 + tt, ND - 1)];
        }
        __syncthreads();
        float a0 = 0.f, a1 = 0.f, as = 0.f;
        const int n1 = (ch == 7) ? 127 : 128;        // G1 needs global t <= 1022
        for (int t = 0; t < 128; ++t) {
            const float vd  = Dch[d][t];
            const float ve  = Dch[e][t];
            const float ve1 = (t < n1) ? Dch[e][t + 1] : 0.f;
            a0 = fmaf(vd, ve, a0);
            a1 = fmaf(vd, ve1, a1);
            as += vd;
        }
        float* gpb = gp + (b * 8 + ch) * GPS;
        gpb[tid] = a0;
        gpb[256 + tid] = a1;
        if (e == 0) {
            gpb[512 + d] = as;
            if (ch == 0) gpb[528 + d] = Dch[d][0];
            if (ch == 7) gpb[544 + d] = Dch[d][127];     // global t=1023
        }
        return;
    }
    // x transpose -> bf16, tile 64c x 64n
    unsigned short (*xb)[72] = (unsigned short (*)[72])sm;  // [n-local][c], 9216 B
    const int i2 = blk - 184;
    const int b  = i2 >> 6;
    const int n0 = (i2 & 63) * 64;
    const int c  = tid >> 2;
    const int q  = tid & 3;
#pragma unroll
    for (int rep = 0; rep < 4; ++rep) {
        const int nl = q * 16 + rep * 4;
        const float4 v = *(const float4*)(x + (size_t)(b * C + c) * N + n0 + nl);
        xb[nl + 0][c] = f2bf(v.x);
        xb[nl + 1][c] = f2bf(v.y);
        xb[nl + 2][c] = f2bf(v.z);
        xb[nl + 3][c] = f2bf(v.w);
    }
    __syncthreads();
#pragma unroll
    for (int pass = 0; pass < 2; ++pass) {
        const int row  = (tid >> 3) + pass * 32;
        const int part = tid & 7;
        const uint4 v = *(const uint4*)(&xb[row][part * 8]);
        *(uint4*)(xt + (size_t)(b * N + n0 + row) * C + part * 8) = v;
    }
}

// K2: one block per (b, 32-l tile). Fully fused (see R4 notes); phase D edge
// clamp FIXED: when the interp's lo-tap index goes negative the reference's
// src-clip collapses the lerp to V[0] exactly -> force both taps to 0.
__global__ __launch_bounds__(256)
void k2(const float* __restrict__ deep, const float* __restrict__ conv_w,
        const float* __restrict__ conv_b, const float* __restrict__ gp,
        const unsigned short* __restrict__ xt, const unsigned short* __restrict__ wb,
        float* __restrict__ out)
{
    __shared__ __align__(16) char sm[40448];
    unsigned short* phi   = (unsigned short*)sm;       // 29184 B (LT x PLD)
    float*          Dw    = (float*)sm;                // alias phi: 12t x 16d floats
    float*          qpart = (float*)(sm + 1024);       // alias phi: 8 x 64 floats
    unsigned short* xtile = (unsigned short*)(sm + 29184);  // 38 x 64 u16
    float*          Vt    = (float*)(sm + 34048);      // 12 x 64
    float*          Gs    = (float*)(sm + 37120);      // 560 floats
    float*          mcs   = (float*)(sm + 39360);      // 64
    float*          scs   = (float*)(sm + 39616);      // 64

    const int b   = blockIdx.y;
    const int l0  = blockIdx.x * LT;
    const int t0  = l0 >> 2;
    const int tid = threadIdx.x;
    const int c   = tid & 63;
    const int seg = tid >> 6;

    // ---- A: staging ----
    for (int u = tid; u < GPS; u += 256) {             // Gram sums / vectors
        float v = 0.f;
        if (u < 528) {
#pragma unroll
            for (int ch = 0; ch < 8; ++ch) v += gp[(b * 8 + ch) * GPS + u];
        } else if (u < 544) {
            v = gp[(b * 8 + 0) * GPS + u];             // d0
        } else {
            v = gp[(b * 8 + 7) * GPS + u];             // dN
        }
        Gs[u] = v;
    }
    for (int u = tid; u < 38 * 8; u += 256) {          // x window rows (bf16, contiguous)
        const int row = u >> 3, part = u & 7;
        const int n = reflect(l0 - 3 + row);
        const uint4 v = *(const uint4*)(xt + (size_t)(b * N + n) * C + part * 8);
        *(uint4*)(xtile + row * 64 + part * 8) = v;
    }
    if (tid < 192) {                                   // deep t-window [t0-2, t0+9]
        const int ti = tid >> 4, d = tid & 15;
        const int t = min(max(t0 - 2 + ti, 0), ND - 1);
        Dw[ti * 16 + d] = deep[(b * DC + d) * ND + t];
    }
    __syncthreads();

    // ---- B: Vt + stats partials ----
    float w[DC];
    {
        const float4* wr = (const float4*)(conv_w + c * DC);
#pragma unroll
        for (int p = 0; p < 4; ++p) {
            const float4 v = wr[p];
            w[4 * p] = v.x; w[4 * p + 1] = v.y; w[4 * p + 2] = v.z; w[4 * p + 3] = v.w;
        }
    }
#pragma unroll
    for (int p = 0; p < 3; ++p) {
        const int ti = seg + 4 * p;
        float a = 0.f;
#pragma unroll
        for (int d = 0; d < DC; ++d) a = fmaf(w[d], Dw[ti * 16 + d], a);
        Vt[ti * 64 + c] = a;
    }
    {   // Q0/Q1 partials over d-range [4seg, 4seg+4)
        float q0 = 0.f, q1 = 0.f;
#pragma unroll
        for (int dd = 0; dd < 4; ++dd) {
            const int d = 4 * seg + dd;
            float i0 = 0.f, i1 = 0.f;
#pragma unroll
            for (int e = 0; e < DC; ++e) {
                i0 = fmaf(w[e], Gs[d * 16 + e], i0);
                i1 = fmaf(w[e], Gs[256 + d * 16 + e], i1);
            }
            q0 = fmaf(w[d], i0, q0);
            q1 = fmaf(w[d], i1, q1);
        }
        qpart[seg * 64 + c] = q0;
        qpart[256 + seg * 64 + c] = q1;
    }
    __syncthreads();

    // ---- C: finalize stats (threads 0..63) ----
    if (tid < 64) {
        const float Q0 = qpart[c] + qpart[64 + c] + qpart[128 + c] + qpart[192 + c];
        const float Q1 = qpart[256 + c] + qpart[320 + c] + qpart[384 + c] + qpart[448 + c];
        float wS = 0.f, V0 = 0.f, VN = 0.f;
#pragma unroll
        for (int d = 0; d < DC; ++d) {
            wS = fmaf(w[d], Gs[512 + d], wS);
            V0 = fmaf(w[d], Gs[528 + d], V0);
            VN = fmaf(w[d], Gs[544 + d], VN);
        }
        const float cb   = conv_b[c];
        const float mean = wS * (1.f / 1024.f) + cb;
        const float S2   = 2.625f * Q0 + 1.375f * Q1 + 0.6875f * (V0 * V0 + VN * VN)
                         + 8.f * cb * wS + 4096.f * cb * cb;
        const float var  = (S2 - 4096.f * mean * mean) * (1.f / 4095.f);   // ddof=1
        mcs[c] = wS * (1.f / 1024.f);         // mean - cb (y-part already excludes cb)
        scs[c] = 0.5f / (var + 1e-9f);        // GAMA/(var+EPS)
    }
    __syncthreads();

    // ---- D: phi ----
    {
        const int base = l0 + seg * 8;
        const float mc = mcs[c], sc = scs[c];
        float xsv[14], xvf[14];
#pragma unroll
        for (int i = 0; i < 14; ++i) {
            const int j  = base - 3 + i;
            const int ja = (j < 0) ? -j : j;
            const int jr = min(ja, 2 * N - 2 - ja);          // reflect
            const int t  = jr >> 2;
            const int r  = jr & 3;
            // taps: r<2 -> (t-1,t) w=(0.375,0.125); r>=2 -> (t,t+1) w=(0.875,0.625)
            const float wa = (r & 1) ? ((r & 2) ? 0.625f : 0.125f)
                                     : ((r & 2) ? 0.875f : 0.375f);
            int tA = t - 1 + (r >> 1);
            int tB = tA + 1;
            if (tA < 0) { tA = 0; tB = 0; }   // src clipped to 0 -> xs = V[0] exactly
            if (tB > ND - 1) tB = ND - 1;     // src clipped to 1023 -> V[1023]
            const int ia = tA - t0 + 2;                       // in [0,11]
            const int ib = tB - t0 + 2;
            const float vl = wa * Vt[ia * 64 + c] + (1.f - wa) * Vt[ib * 64 + c];
            xsv[i] = (vl - mc) * sc;
            xvf[i] = bf2f(xtile[(seg * 8 + i) * 64 + c]);
        }
        unsigned short* pcol = phi + c * KW;
#pragma unroll
        for (int li = 0; li < 8; ++li) {
            const float cen = xsv[li + 3];
            float u[KW];
            float s = 0.25f;                  // tap k=3: d=0 -> loss/4 = 1/4 exactly
            u[3] = 0.25f;
#pragma unroll
            for (int k = 0; k < KW; ++k) {
                if (k == 3) continue;
                const float d = fabsf(xsv[li + k] - cen);
                const float e = __expf(-2.f * d);   // 1-tanh^2 = 4e^{-2d}/(1+e^{-2d})^2
                const float t = 1.f + e;
                const float uk = e * rcpf(t * t);
                u[k] = uk;
                s += uk;
            }
            const float al = rcpf(s);
            unsigned short* pr = pcol + (seg * 8 + li) * PLD;
#pragma unroll
            for (int k = 0; k < KW; ++k) pr[k] = f2bf(u[k] * al * xvf[li + k]);
        }
    }
    __syncthreads();

    // ---- E: MFMA (identical to verified R3 phase 2) ----
    const int lane = tid & 63;
    const int quad = lane >> 4;
    const int rr   = lane & 15;
    const int o0   = seg * 32;

    floatx4 acc00 = {0.f, 0.f, 0.f, 0.f}, acc01 = acc00, acc10 = acc00, acc11 = acc00;
    const unsigned short* wrow0 = wb + (o0 + rr) * F + quad * 8;
    const unsigned short* wrow1 = wrow0 + 16 * F;
    const unsigned short* prow0 = phi + rr * PLD + quad * 8;
    const unsigned short* prow1 = prow0 + 16 * PLD;

    for (int s = 0; s < F / 32; ++s) {
        const int f0 = 32 * s;
        const short8 a0 = *(const short8*)(wrow0 + f0);
        const short8 a1 = *(const short8*)(wrow1 + f0);
        const short8 b0 = *(const short8*)(prow0 + f0);
        const short8 b1 = *(const short8*)(prow1 + f0);
        acc00 = __builtin_amdgcn_mfma_f32_16x16x32_bf16(a0, b0, acc00, 0, 0, 0);
        acc01 = __builtin_amdgcn_mfma_f32_16x16x32_bf16(a0, b1, acc01, 0, 0, 0);
        acc10 = __builtin_amdgcn_mfma_f32_16x16x32_bf16(a1, b0, acc10, 0, 0, 0);
        acc11 = __builtin_amdgcn_mfma_f32_16x16x32_bf16(a1, b1, acc11, 0, 0, 0);
    }

    float* ob = out + (size_t)(b * CO) * N + l0;
#pragma unroll
    for (int i = 0; i < 4; ++i) {
        const int om = quad * 4 + i;
        ob[(o0 + om) * N      + rr     ] = acc00[i];
        ob[(o0 + om) * N      + 16 + rr] = acc01[i];
        ob[(o0 + 16 + om) * N + rr     ] = acc10[i];
        ob[(o0 + 16 + om) * N + 16 + rr] = acc11[i];
    }
}
} // namespace

extern "C" void kernel_launch(void* const* d_in, const int* in_sizes, int n_in,
                              void* d_out, int out_size, void* d_ws, size_t ws_size,
                              hipStream_t stream)
{
    const float* deep   = (const float*)d_in[0];
    const float* x      = (const float*)d_in[1];
    const float* conv_w = (const float*)d_in[2];
    const float* conv_b = (const float*)d_in[3];
    const float* fc_w   = (const float*)d_in[4];
    float* out = (float*)d_out;

    unsigned short* wbuf = (unsigned short*)((char*)d_ws + WB_OFF);
    float*          gp   = (float*)((char*)d_ws + GP_OFF);
    unsigned short* xt   = (unsigned short*)((char*)d_ws + XT_OFF);

    hipLaunchKernelGGL(k0, dim3(56 + 128 + 1024), dim3(256), 0, stream,
                       deep, x, fc_w, wbuf, gp, xt);
    hipLaunchKernelGGL(k2, dim3(N / LT, Bc), dim3(256), 0, stream,
                       deep, conv_w, conv_b, gp, xt, wbuf, out);
}